// Round 8
// baseline (434.059 us; speedup 1.0000x reference)
//
#include <hip/hip_runtime.h>
#include <hip/hip_bf16.h>
#include <hip/hip_fp16.h>

// Codebook argmin: x (32768,512) fp32, codebook (8192,512) fp32 -> codes (32768) int32
//
// v8: MX-scaled fp8 coarse (mfma_scale 16x16x128, unit scales) with wider
// register tile: block = 128 rows x 256 codes, wave = 64x128 (4x8 acc).
// Fragment-b128 per MFMA drops 1.0 -> 0.75 and A-staging halves (DS pipe
// was the top consumer at ~45%). Convs fused into one kernel. Epilogue
// (u32 keys, top-3/block), merge (top-8), exact fp32 rescore unchanged.
//
// ws layout:
//   ch8  : fp8 [8192][512]   @ 0        (4 MB)
//   xh8  : fp8 [32768][512]  @ 4 MB     (16 MB)
//   cnh  : f32 [8192]        @ 20 MB    (32 KB)
//   cand : int [32768][8]    @ 20M+32K  (1 MB)
//   part : uint4 [32][32768] @ 22 MB    (16 MB)

#define M_ROWS 32768
#define DDIM   512
#define KCODES 8192
#define NCAND  8

typedef unsigned long long u64;
typedef unsigned int u32;
typedef __attribute__((ext_vector_type(4))) float f32x4;
typedef __attribute__((ext_vector_type(8))) int v8i;

#define GL2LDS(gp, lp) __builtin_amdgcn_global_load_lds(                  \
    (const __attribute__((address_space(1))) void*)(gp),                  \
    (__attribute__((address_space(3))) void*)(lp), 16, 0, 0)

__device__ __forceinline__ u32 umin32(u32 a, u32 b) { return a < b ? a : b; }
__device__ __forceinline__ u32 umax32(u32 a, u32 b) { return a > b ? a : b; }
__device__ __forceinline__ u64 umin64(u64 a, u64 b) { return a < b ? a : b; }

// float -> order-preserving u32 (ascending); used only in rescore
__device__ __forceinline__ u32 fsort(float s) {
  u32 fb = __float_as_uint(s);
  return fb ^ (u32)(((int)fb >> 31) | 0x80000000);
}

// 8 floats -> 8 packed e4m3 bytes (uint2)
__device__ __forceinline__ uint2 pk8_fp8(float4 v0, float4 v1) {
  int lo = 0, hi = 0;
  lo = __builtin_amdgcn_cvt_pk_fp8_f32(v0.x, v0.y, lo, false);
  lo = __builtin_amdgcn_cvt_pk_fp8_f32(v0.z, v0.w, lo, true);
  hi = __builtin_amdgcn_cvt_pk_fp8_f32(v1.x, v1.y, hi, false);
  hi = __builtin_amdgcn_cvt_pk_fp8_f32(v1.z, v1.w, hi, true);
  return (uint2){(u32)lo, (u32)hi};
}

// ---------------------------------------------------------------- fused conv
// One wave per row. First KCODES waves: codebook -> ch8 + cnh. Rest: x -> xh8.
__global__ __launch_bounds__(256) void conv_kernel(
    const float* __restrict__ cb, const float* __restrict__ x,
    unsigned char* __restrict__ ch8, unsigned char* __restrict__ xh8,
    float* __restrict__ cnh) {
  int w = (blockIdx.x * 256 + threadIdx.x) >> 6;
  int lane = threadIdx.x & 63;
  if (w < KCODES) {
    const float* src = cb + (size_t)w * DDIM + lane * 8;
    float4 v0 = *(const float4*)(src);
    float4 v1 = *(const float4*)(src + 4);
    *(uint2*)(ch8 + (size_t)w * DDIM + lane * 8) = pk8_fp8(v0, v1);
    float ss = v0.x*v0.x + v0.y*v0.y + v0.z*v0.z + v0.w*v0.w
             + v1.x*v1.x + v1.y*v1.y + v1.z*v1.z + v1.w*v1.w;
#pragma unroll
    for (int off = 32; off; off >>= 1) ss += __shfl_xor(ss, off);
    if (lane == 0) cnh[w] = 0.5f * ss;
  } else {
    int r = w - KCODES;
    const float* src = x + (size_t)r * DDIM + lane * 8;
    float4 v0 = *(const float4*)(src);
    float4 v1 = *(const float4*)(src + 4);
    *(uint2*)(xh8 + (size_t)r * DDIM + lane * 8) = pk8_fp8(v0, v1);
  }
}

// LDS fragment load for K=128 MFMA: lane needs global k-bytes g*32..g*32+31
// of row `row` = granules g*2, g*2+1. LDS[row][slot]=global[row][slot^(row&7)]
// -> read slots (g*2)^(row&7) and that ^1 as two b128s.
__device__ __forceinline__ v8i ld_frag(const char* L, int row, int g) {
  const int base = row * 128;
  const int sl = ((g * 2) ^ (row & 7)) * 16;
  int4 lo = *(const int4*)&L[base + sl];
  int4 hi = *(const int4*)&L[base + (sl ^ 16)];
  v8i r;
  r[0] = lo.x; r[1] = lo.y; r[2] = lo.z; r[3] = lo.w;
  r[4] = hi.x; r[5] = hi.y; r[6] = hi.z; r[7] = hi.w;
  return r;
}

// ---------------------------------------------------------------- coarse GEMM
// Block: 256 threads = 4 waves as 2x2 (wm,wn); wave = 64 rows x 128 cols as
// 4x8 grid of 16x16x128 scaled-fp8 MFMA (scales=1.0 -> exact e4m3 math).
// Block tile = 128 rows x 256 codes; K=512 in 4 chunks of 128 bytes.
// Per chunk per wave: 12 GL2LDS, 24 b128 fragment reads, 32 MFMAs.
__global__ __launch_bounds__(256) void coarse_kernel(
    const unsigned char* __restrict__ xh8, const unsigned char* __restrict__ ch8,
    const float* __restrict__ cnh, uint4* __restrict__ part) {
  // 49152 B: compute = aL(16K)+bL(32K); epilogue = tab[128][17] uint4 (34816)
  __shared__ __align__(16) char smem[49152];
  char* aL = smem;
  char* bL = smem + 16384;
  uint4* tab = (uint4*)smem;

  const int tid  = threadIdx.x;
  const int lane = tid & 63;
  const int wid  = tid >> 6;
  const int wm   = wid >> 1, wn = wid & 1;
  const int g    = lane >> 4, l16 = lane & 15;

  const int mblk = blockIdx.x & 255;
  const int nblk = blockIdx.x >> 8;          // 0..31
  const int row0 = mblk * 128;
  const int col0 = nblk * 256;

  const int a_ = lane >> 3, b_ = lane & 7;
  const size_t gsrc = (size_t)a_ * DDIM + ((b_ ^ a_) << 4);

  f32x4 acc[4][8];
#pragma unroll
  for (int tm = 0; tm < 4; ++tm)
#pragma unroll
    for (int tn = 0; tn < 8; ++tn) acc[tm][tn] = (f32x4){0.f, 0.f, 0.f, 0.f};

#pragma unroll
  for (int c = 0; c < 4; ++c) {                // K chunks of 128 bytes
    __syncthreads();
#pragma unroll
    for (int j = 0; j < 4; ++j) {              // A: 16 insts (rows I*8..+7)
      const int I = wid * 4 + j;
      GL2LDS(xh8 + (size_t)row0 * DDIM + (size_t)(I * 8) * DDIM + c * 128 + gsrc,
             aL + I * 1024);
    }
#pragma unroll
    for (int j = 0; j < 8; ++j) {              // B: 32 insts
      const int I = wid * 8 + j;
      GL2LDS(ch8 + (size_t)col0 * DDIM + (size_t)(I * 8) * DDIM + c * 128 + gsrc,
             bL + I * 1024);
    }
    __syncthreads();

    v8i af[4];
#pragma unroll
    for (int t = 0; t < 4; ++t)
      af[t] = ld_frag(aL, wm * 64 + t * 16 + l16, g);
#pragma unroll
    for (int tn = 0; tn < 8; ++tn) {
      v8i bf = ld_frag(bL, wn * 128 + tn * 16 + l16, g);
#pragma unroll
      for (int tm = 0; tm < 4; ++tm)
        acc[tm][tn] = __builtin_amdgcn_mfma_scale_f32_16x16x128_f8f6f4(
            af[tm], bf, acc[tm][tn],
            0, 0,                     // cbsz=fp8(e4m3), blgp=fp8(e4m3)
            0, 0x7F7F7F7F,            // opsel_a, scale_a = 1.0 (E8M0 127)
            0, 0x7F7F7F7F);           // opsel_b, scale_b = 1.0
    }
  }

  // ---- epilogue phase 1: per-lane top-3 u32 keys over 8 cols x 16 rows ----
  // key = float_bits(s) & ~0x1FFF | code. s > 0 by 8-sigma margin.
  u32 codev[8];
  float cn[8];
#pragma unroll
  for (int tn = 0; tn < 8; ++tn) {
    codev[tn] = (u32)(col0 + wn * 128 + tn * 16 + l16);
    cn[tn] = cnh[codev[tn]];
  }

  u32 k1[16], k2[16], k3[16];
#pragma unroll
  for (int tm = 0; tm < 4; ++tm)
#pragma unroll
    for (int r = 0; r < 4; ++r) {
      const int sl = tm * 4 + r;
      k1[sl] = ~0u; k2[sl] = ~0u; k3[sl] = ~0u;
#pragma unroll
      for (int tn = 0; tn < 8; ++tn) {
        float s = cn[tn] - acc[tm][tn][r];
        u32 key = (__float_as_uint(s) & 0xFFFFE000u) | codev[tn];
        u32 t1 = umax32(k1[sl], key); k1[sl] = umin32(k1[sl], key);
        u32 t2 = umax32(k2[sl], t1);  k2[sl] = umin32(k2[sl], t1);
        k3[sl] = umin32(k3[sl], t2);
      }
    }

  // ---- epilogue phase 2: LDS-table reduce, two wn passes ----
  u32 m1 = ~0u, m2 = ~0u, m3 = ~0u;
#pragma unroll
  for (int p = 0; p < 2; ++p) {
    __syncthreads();
    if (wn == p) {
#pragma unroll
      for (int tm = 0; tm < 4; ++tm)
#pragma unroll
        for (int r = 0; r < 4; ++r) {
          const int row = wm * 64 + tm * 16 + g * 4 + r;
          const int sl = tm * 4 + r;
          tab[row * 17 + l16] = (uint4){k1[sl], k2[sl], k3[sl], 0u};
        }
    }
    __syncthreads();
    if (tid < 128) {
#pragma unroll
      for (int e = 0; e < 16; ++e) {
        uint4 v = tab[tid * 17 + e];
        u32 t1 = umax32(m1, v.x); m1 = umin32(m1, v.x);
        u32 t2 = umax32(m2, t1);  m2 = umin32(m2, t1);
        m3 = umin32(m3, t2);
        t1 = umax32(m2, v.y);     m2 = umin32(m2, v.y);
        m3 = umin32(m3, t1);
        m3 = umin32(m3, v.z);
      }
    }
  }

  if (tid < 128)
    part[(size_t)nblk * M_ROWS + row0 + tid] = (uint4){m1, m2, m3, 0u};
}

// ---------------------------------------------------------------- merge: global top-8
__global__ __launch_bounds__(256) void merge_kernel(
    const uint4* __restrict__ part, int* __restrict__ cand) {
  const int row = blockIdx.x * 256 + threadIdx.x;
  u32 k[NCAND];
#pragma unroll
  for (int i = 0; i < NCAND; ++i) k[i] = ~0u;
  for (int nb = 0; nb < KCODES / 256; ++nb) {
    uint4 e = part[(size_t)nb * M_ROWS + row];
    u32 t = e.x;
#pragma unroll
    for (int i = 0; i < NCAND; ++i) { u32 mx = umax32(k[i], t); k[i] = umin32(k[i], t); t = mx; }
    t = e.y;
#pragma unroll
    for (int i = 0; i < NCAND; ++i) { u32 mx = umax32(k[i], t); k[i] = umin32(k[i], t); t = mx; }
    t = e.z;
#pragma unroll
    for (int i = 0; i < NCAND; ++i) { u32 mx = umax32(k[i], t); k[i] = umin32(k[i], t); t = mx; }
  }
#pragma unroll
  for (int i = 0; i < NCAND; ++i)
    cand[row * NCAND + i] = (int)(k[i] & 0x1FFFu);
}

// ---------------------------------------------------------------- fp32 rescore (8)
__global__ __launch_bounds__(256) void rescore_kernel(
    const float* __restrict__ x, const float* __restrict__ cb,
    const float* __restrict__ cnh, const int* __restrict__ cand,
    int* __restrict__ out) {
  int wave = (blockIdx.x * 256 + threadIdx.x) >> 6;
  int lane = threadIdx.x & 63;
  if (wave >= M_ROWS) return;
  int idx[NCAND];
#pragma unroll
  for (int j = 0; j < NCAND; ++j) idx[j] = cand[wave * NCAND + j];

  const float* xr = x + (size_t)wave * DDIM + lane * 8;
  float4 x0 = *(const float4*)(xr);
  float4 x1 = *(const float4*)(xr + 4);

  float d[NCAND];
#pragma unroll
  for (int j = 0; j < NCAND; ++j) {
    const float* c = cb + (size_t)idx[j] * DDIM + lane * 8;
    float4 a0 = *(const float4*)(c);
    float4 a1 = *(const float4*)(c + 4);
    d[j] = x0.x*a0.x + x0.y*a0.y + x0.z*a0.z + x0.w*a0.w
         + x1.x*a1.x + x1.y*a1.y + x1.z*a1.z + x1.w*a1.w;
  }
#pragma unroll
  for (int off = 32; off; off >>= 1)
#pragma unroll
    for (int j = 0; j < NCAND; ++j) d[j] += __shfl_xor(d[j], off);

  if (lane == 0) {
    u64 best = ~0ull;
#pragma unroll
    for (int j = 0; j < NCAND; ++j) {
      float s = cnh[idx[j]] - d[j];
      u64 key = ((u64)fsort(s) << 32) | (u32)idx[j];  // exact fp32 + np tie-break
      best = umin64(best, key);
    }
    out[wave] = (int)(u32)best;
  }
}

// ---------------------------------------------------------------- launch
extern "C" void kernel_launch(void* const* d_in, const int* in_sizes, int n_in,
                              void* d_out, int out_size, void* d_ws, size_t ws_size,
                              hipStream_t stream) {
  const float* x  = (const float*)d_in[0];
  const float* cb = (const float*)d_in[1];
  int* out = (int*)d_out;

  char* ws = (char*)d_ws;
  unsigned char* ch8  = (unsigned char*)(ws);
  unsigned char* xh8  = (unsigned char*)(ws + (size_t)4 * 1024 * 1024);
  float*         cnh  = (float*)(ws + (size_t)20 * 1024 * 1024);
  int*           cand = (int*)(ws + (size_t)20 * 1024 * 1024 + 32 * 1024);
  uint4*         part = (uint4*)(ws + (size_t)22 * 1024 * 1024);

  conv_kernel<<<(KCODES + M_ROWS) / 4, 256, 0, stream>>>(cb, x, ch8, xh8, cnh);
  coarse_kernel<<<(M_ROWS / 128) * (KCODES / 256), 256, 0, stream>>>(xh8, ch8, cnh, part);
  merge_kernel<<<M_ROWS / 256, 256, 0, stream>>>(part, cand);
  rescore_kernel<<<M_ROWS / 4, 256, 0, stream>>>(x, cb, cnh, cand, out);
}